// Round 12
// baseline (157.767 us; speedup 1.0000x reference)
//
#include <hip/hip_runtime.h>
#include <stdint.h>

#define N 4096
#define NF 6
#define NO 16

typedef _Float16 half8 __attribute__((ext_vector_type(8)));
typedef _Float16 half2t __attribute__((ext_vector_type(2)));
typedef float floatx4 __attribute__((ext_vector_type(4)));

// ---------------- workspace layout (bytes) ----------------
#define OFF_WHF  0          // 8*4096*16 fp16 = 1 MB, B-fragment order [h][mtile][lane][j]
#define OFF_EN   1048576    // exp(es)      f32 [h][n]
#define OFF_EN2  1179648    // exp(0.2 es)  f32 [h][n]
#define OFF_FH   1310720    // exp(ed)      fp16 [h][n] 64 KB
#define OFF_F2H  1376256    // exp(0.2 ed)  fp16 [h][n] 64 KB
#define OFF_X2   1441792    // 4096*128 f32 = 2 MB
#define OFF_WH2  3538944    // 4096 f32
#define OFF_G1   3555328    // exp(ed2)     fp16, 8 KB
#define OFF_G2   3563520    // exp(0.2 ed2) fp16, 8 KB
#define OFF_BITS 3571712    // TRANSPOSED bitmask u64 [64 words][4096 rows] = 2 MB

// ---- kernel 1: Wh = x@W per head -> fp16 B-frag; exp tables of es/ed ----
__global__ __launch_bounds__(256) void k_wh(const float* __restrict__ x,
                                            const float* __restrict__ W,
                                            const float* __restrict__ a,
                                            _Float16* __restrict__ Whf,
                                            float* __restrict__ en,
                                            float* __restrict__ en2,
                                            _Float16* __restrict__ fh,
                                            _Float16* __restrict__ f2h) {
    int tid = blockIdx.x * 256 + threadIdx.x;   // 32768 threads: (n,h)
    int n = tid >> 3, h = tid & 7;
    float xf[NF];
#pragma unroll
    for (int f = 0; f < NF; ++f) xf[f] = x[n * NF + f];
    float wh[NO];
#pragma unroll
    for (int o = 0; o < NO; ++o) {
        float s = 0.f;
#pragma unroll
        for (int f = 0; f < NF; ++f) s = fmaf(xf[f], W[(h * NF + f) * NO + o], s);
        wh[o] = s;
    }
    float s1 = 0.f, s2 = 0.f;
#pragma unroll
    for (int o = 0; o < NO; ++o) {
        s1 = fmaf(wh[o], a[h * 32 + o], s1);
        s2 = fmaf(wh[o], a[h * 32 + 16 + o], s2);
    }
    // B-fragment scatter: lane q*16+o of an m-tile holds B[k=q*8+j][o]
    int tile = n >> 5, q = (n >> 3) & 3, j = n & 7;
    _Float16* base = Whf + ((size_t)((h << 7) + tile) << 9) + j;
#pragma unroll
    for (int o = 0; o < NO; ++o) base[(size_t)(((q << 4) + o) << 3)] = (_Float16)wh[o];
    int idx = (h << 12) + n;
    en [idx] = __expf(s1);
    en2[idx] = __expf(0.2f * s1);
    fh [idx] = (_Float16)__expf(s2);
    f2h[idx] = (_Float16)__expf(0.2f * s2);
}

// ---- kernel 2: pack adjacency to TRANSPOSED bitmask [word][row] ----
__global__ __launch_bounds__(256) void k_bits(const int* __restrict__ adj,
                                              unsigned long long* __restrict__ bits) {
    int lane = threadIdx.x & 63;
    int wv = threadIdx.x >> 6;
    int n = blockIdx.x;
    int wbase = wv << 4;
    const int* row = adj + (size_t)n * N + (wbase << 6) + lane;
    int v[16];
#pragma unroll
    for (int i = 0; i < 16; ++i) v[i] = row[i << 6];
    unsigned long long b[16];
#pragma unroll
    for (int i = 0; i < 16; ++i) b[i] = __ballot(v[i] != 0);
    if (lane == 0) {
#pragma unroll
        for (int i = 0; i < 16; ++i)
            bits[((size_t)(wbase + i) << 12) + n] = b[i];
    }
}

// ---- kernel 3: layer-1 attention, packed-fp16 + MFMA, LDS tables, t=2 ----
// R12: byte-indexed mask LUT (256 x 16 B, one ds_read_b128 per t instead of
// two b64) + unroll 2 for cross-step ILP on the bits->lut dependent chain.
// e = max(exp(es)exp(ed), exp(.2es)exp(.2ed)); mask via AND (fp16 +0 = 0x0).
// grid = 8 heads * 128 groups of 32 rows = 1024 blocks; block = 4 waves;
// wave wv covers m in [wv*1024,...) in 32 steps of 32, 2 row-tiles each.
// A-frag A[n=lane&15][k=q*8+j]; C/D col=lane&15, row=q*4+reg.
__global__ __launch_bounds__(256, 4) void k_attn1(const _Float16* __restrict__ Whf,
                                                  const float* __restrict__ en,
                                                  const float* __restrict__ en2,
                                                  const _Float16* __restrict__ fh,
                                                  const _Float16* __restrict__ f2h,
                                                  const uint32_t* __restrict__ bits,
                                                  float* __restrict__ x2) {
    int h = blockIdx.x >> 7;
    int rg = blockIdx.x & 127;
    int lane = threadIdx.x & 63;
    int wv = threadIdx.x >> 6;          // 0..3
    int l15 = lane & 15, q = lane >> 4, qb = q << 3;
    int rowb = rg << 5;

    __shared__ alignas(16) _Float16 sF[4096];   // exp(ed) for this head
    __shared__ alignas(16) _Float16 sG[4096];   // exp(0.2 ed)
    __shared__ float red[32][17];               // [row][o 0..15, den]
    __shared__ alignas(16) uint4 lut[256];      // byte -> 4 pair half-masks

    {   // cooperative staging: 2 x 8 KB, coalesced float4
        const floatx4* Fg = (const floatx4*)(fh  + (h << 12));
        const floatx4* Gg = (const floatx4*)(f2h + (h << 12));
        floatx4* sFv = (floatx4*)sF;
        floatx4* sGv = (floatx4*)sG;
#pragma unroll
        for (int i = threadIdx.x; i < 512; i += 256) {
            sFv[i] = Fg[i];
            sGv[i] = Gg[i];
        }
    }
    for (int i = threadIdx.x; i < 32 * 17; i += 256) ((float*)red)[i] = 0.f;
    {
        uint32_t v = threadIdx.x;       // 256 threads -> 256 entries
        uint4 e4;
        e4.x = ((v &   1u) ? 0x0000FFFFu : 0u) | ((v &   2u) ? 0xFFFF0000u : 0u);
        e4.y = ((v &   4u) ? 0x0000FFFFu : 0u) | ((v &   8u) ? 0xFFFF0000u : 0u);
        e4.z = ((v &  16u) ? 0x0000FFFFu : 0u) | ((v &  32u) ? 0xFFFF0000u : 0u);
        e4.w = ((v &  64u) ? 0x0000FFFFu : 0u) | ((v & 128u) ? 0xFFFF0000u : 0u);
        lut[v] = e4;
    }
    __syncthreads();

    half2t ena2[2], enb2[2];
    int rowoff[2];
#pragma unroll
    for (int t = 0; t < 2; ++t) {
        int row = rowb + (t << 4) + l15;
        _Float16 ha = (_Float16)en [(h << 12) + row];
        _Float16 hb = (_Float16)en2[(h << 12) + row];
        ena2[t] = (half2t){ha, ha};
        enb2[t] = (half2t){hb, hb};
        rowoff[t] = row << 1;           // u32 index into bitsT column
    }

    floatx4 acc[2], accd[2];
#pragma unroll
    for (int t = 0; t < 2; ++t)
#pragma unroll
        for (int r = 0; r < 4; ++r) { acc[t][r] = 0.f; accd[t][r] = 0.f; }

    half8 ones;
#pragma unroll
    for (int j = 0; j < 8; ++j) ones[j] = (_Float16)1.0f;

#pragma unroll 2
    for (int step = 0; step < 32; ++step) {
        int m0 = (wv << 10) + (step << 5);
        union { half8 v; half2t h2[4]; uint32_t u[4]; } F, G;
        F.v = *(const half8*)(sF + m0 + qb);      // ds_read_b128, quad-broadcast
        G.v = *(const half8*)(sG + m0 + qb);
        half8 bfrag = *(const half8*)(Whf + ((size_t)((h << 7) + (m0 >> 5)) << 9) + (lane << 3));
        int wbase = ((m0 >> 6) << 13) + ((m0 >> 5) & 1);
#pragma unroll
        for (int t = 0; t < 2; ++t) {
            uint32_t w = (bits[wbase + rowoff[t]] >> qb) & 0xFFu;
            uint4 m4 = lut[w];                    // one ds_read_b128
            uint32_t msk[4] = {m4.x, m4.y, m4.z, m4.w};
            union { half8 v; uint32_t u[4]; } A;
#pragma unroll
            for (int p = 0; p < 4; ++p) {
                half2t e = __builtin_elementwise_max(ena2[t] * F.h2[p], enb2[t] * G.h2[p]);
                A.u[p] = __builtin_bit_cast(uint32_t, e) & msk[p];
            }
            acc[t]  = __builtin_amdgcn_mfma_f32_16x16x32_f16(A.v, bfrag, acc[t],  0, 0, 0);
            accd[t] = __builtin_amdgcn_mfma_f32_16x16x32_f16(A.v, ones,  accd[t], 0, 0, 0);
        }
    }

    // combine 4 wave partials via LDS atomics
#pragma unroll
    for (int t = 0; t < 2; ++t) {
#pragma unroll
        for (int r = 0; r < 4; ++r)
            atomicAdd(&red[(t << 4) + (q << 2) + r][l15], acc[t][r]);
        if (l15 == 0) {
#pragma unroll
            for (int r = 0; r < 4; ++r)
                atomicAdd(&red[(t << 4) + (q << 2) + r][16], accd[t][r]);
        }
    }
    __syncthreads();

#pragma unroll
    for (int i = threadIdx.x; i < 512; i += 256) {
        int r2 = i >> 4, c2 = i & 15;
        float v = red[r2][c2] / red[r2][16];
        v = v > 0.f ? v : expm1f(v);                     // jax.nn.elu
        x2[(size_t)(rowb + r2) * 128 + (h << 4) + c2] = v;
    }
}

// ---- kernel 4: Wh2 = x2 @ W_out (C=1), wave per row; fp16 exp tables ----
__global__ __launch_bounds__(256) void k_wh2(const float* __restrict__ x2,
                                             const float* __restrict__ W_out,
                                             const float* __restrict__ a_out,
                                             float* __restrict__ Wh2,
                                             _Float16* __restrict__ g1,
                                             _Float16* __restrict__ g2) {
    int lane = threadIdx.x & 63;
    int n = (blockIdx.x << 2) + (threadIdx.x >> 6);
    const float2* xp = (const float2*)(x2 + (size_t)n * 128);
    const float2* wp = (const float2*)W_out;
    float2 xv = xp[lane], wv2 = wp[lane];
    float s = fmaf(xv.x, wv2.x, xv.y * wv2.y);
#pragma unroll
    for (int off = 32; off; off >>= 1) s += __shfl_xor(s, off);
    if (lane == 0) {
        Wh2[n] = s;
        float ed = s * a_out[1];
        g1[n] = (_Float16)__expf(ed);
        g2[n] = (_Float16)__expf(0.2f * ed);
    }
}

// ---- kernel 5: layer-2 attention, exp-free, block per row, 4 waves ----
__global__ __launch_bounds__(256) void k_attn2(const float* __restrict__ Wh2,
                                               const _Float16* __restrict__ g1,
                                               const _Float16* __restrict__ g2,
                                               const float* __restrict__ a_out,
                                               const unsigned long long* __restrict__ bits,
                                               float* __restrict__ out) {
    int n = blockIdx.x;
    int lane = threadIdx.x & 63;
    int wv = threadIdx.x >> 6;
    float esn = Wh2[n] * a_out[0];
    float En  = __expf(esn);
    float En2 = __expf(0.2f * esn);
    float num = 0.f, den = 0.f;
#pragma unroll
    for (int it = 0; it < 16; ++it) {
        int w = (wv << 4) + it;
        int m = (w << 6) + lane;
        float w2 = Wh2[m];
        float ga = (float)g1[m];
        float gb = (float)g2[m];
        unsigned long long wb = bits[((size_t)w << 12) + n];
        float e = fmaxf(En * ga, En2 * gb);
        e = ((wb >> lane) & 1ull) ? e : 0.f;
        num = fmaf(e, w2, num);
        den += e;
    }
#pragma unroll
    for (int off = 32; off; off >>= 1) {
        num += __shfl_xor(num, off);
        den += __shfl_xor(den, off);
    }
    __shared__ float rn[4], rd[4];
    if (lane == 0) { rn[wv] = num; rd[wv] = den; }
    __syncthreads();
    if (threadIdx.x == 0) {
        float nn = rn[0] + rn[1] + rn[2] + rn[3];
        float dd = rd[0] + rd[1] + rd[2] + rd[3];
        float v = nn / dd;
        out[n] = v > 0.f ? v : expm1f(v);
    }
}

extern "C" void kernel_launch(void* const* d_in, const int* in_sizes, int n_in,
                              void* d_out, int out_size, void* d_ws, size_t ws_size,
                              hipStream_t stream) {
    const float* x     = (const float*)d_in[0];
    const int*   adj   = (const int*)d_in[1];
    const float* W     = (const float*)d_in[2];
    const float* a     = (const float*)d_in[3];
    const float* W_out = (const float*)d_in[4];
    const float* a_out = (const float*)d_in[5];
    float* out = (float*)d_out;

    char* ws = (char*)d_ws;
    _Float16* Whf = (_Float16*)(ws + OFF_WHF);
    float* en  = (float*)(ws + OFF_EN);
    float* en2 = (float*)(ws + OFF_EN2);
    _Float16* fhh  = (_Float16*)(ws + OFF_FH);
    _Float16* f2hh = (_Float16*)(ws + OFF_F2H);
    float* x2  = (float*)(ws + OFF_X2);
    float* Wh2 = (float*)(ws + OFF_WH2);
    _Float16* g1 = (_Float16*)(ws + OFF_G1);
    _Float16* g2 = (_Float16*)(ws + OFF_G2);
    unsigned long long* bits = (unsigned long long*)(ws + OFF_BITS);

    hipLaunchKernelGGL(k_wh,    dim3(128),  dim3(256), 0, stream,
                       x, W, a, Whf, en, en2, fhh, f2hh);
    hipLaunchKernelGGL(k_bits,  dim3(4096), dim3(256), 0, stream, adj, bits);
    hipLaunchKernelGGL(k_attn1, dim3(1024), dim3(256), 0, stream,
                       Whf, en, en2, fhh, f2hh, (const uint32_t*)bits, x2);
    hipLaunchKernelGGL(k_wh2,   dim3(1024), dim3(256), 0, stream, x2, W_out, a_out,
                       Wh2, g1, g2);
    hipLaunchKernelGGL(k_attn2, dim3(4096), dim3(256), 0, stream, Wh2, g1, g2,
                       a_out, bits, out);
}